// Round 1
// 120.065 us; speedup vs baseline: 1.0798x; 1.0798x over previous
//
#include <hip/hip_runtime.h>

#define HH 64
#define WW 64
#define CC 128
#define FF 256
#define NTAP 9
#define KD 1152   // NTAP*CC
#define XELEMS (8 * HH * WW * CC)         // 4194304
#define XCVT_BLOCKS (XELEMS / (256 * 8))  // 2048
#define WT_BLOCKS 144                     // 36864 threads, 8 k each

typedef __attribute__((ext_vector_type(8))) short bf16x8;
typedef __attribute__((ext_vector_type(4))) float floatx4;

__device__ inline unsigned short f2bf(float v) {
  union { float f; unsigned u; } c; c.f = v;
  unsigned r = (c.u + 0x7FFFu + ((c.u >> 16) & 1u)) >> 16;  // RNE
  return (unsigned short)r;
}
__device__ inline float bflo(unsigned u) {
  union { unsigned u; float f; } c; c.u = u << 16; return c.f;
}
__device__ inline float bfhi(unsigned u) {
  union { unsigned u; float f; } c; c.u = u & 0xFFFF0000u; return c.f;
}

// Identical arithmetic path to the previous (verified) interp kernel.
__device__ inline unsigned lerp_word(unsigned u00, unsigned u10, unsigned u01, unsigned u11,
                                     float fy, float fx) {
  float v00 = bflo(u00), v10 = bflo(u10), v01 = bflo(u01), v11 = bflo(u11);
  float tx = v00 + (v10 - v00) * fy;
  float tb = v01 + (v11 - v01) * fy;
  unsigned short rlo = f2bf(tx + (tb - tx) * fx);
  v00 = bfhi(u00); v10 = bfhi(u10); v01 = bfhi(u01); v11 = bfhi(u11);
  tx = v00 + (v10 - v00) * fy;
  tb = v01 + (v11 - v01) * fy;
  unsigned short rhi = f2bf(tx + (tb - tx) * fx);
  return (unsigned)rlo | ((unsigned)rhi << 16);
}

// Tap offsets packed 2 bits each (meshgrid-faithful order, matches old c_iy/c_ix):
// c_iy = {0,0,1,2,2,1,0,2,1} -> 0x18690 ; c_ix = {0,1,1,2,0,2,1,0,2} -> 0x21894
#define IY_PACK 0x18690
#define IX_PACK 0x21894

struct ITap { int b00, b10, b01, b11; float fy, fx; };

__device__ inline ITap interp_setup(const float* __restrict__ offp, int i, int p, int nx) {
  const int n = nx >> 1;
  const float2 o2 = *(const float2*)(offp + 2 * n);
  float cy = (float)(i - 1 + ((IY_PACK >> (2 * n)) & 3)) + o2.x;
  float cx = (float)(p - 1 + ((IX_PACK >> (2 * n)) & 3)) + o2.y;
  cy = fminf(fmaxf(cy, 0.f), 63.f);
  cx = fminf(fmaxf(cx, 0.f), 63.f);
  const float fy0 = floorf(cy), fx0 = floorf(cx);
  const int y0 = (int)fy0, y1 = (int)ceilf(cy);
  const int x0 = (int)fx0, x1 = (int)ceilf(cx);
  ITap t;
  t.b00 = (y0 * WW + x0) * CC;
  t.b10 = (y1 * WW + x0) * CC;
  t.b01 = (y0 * WW + x1) * CC;
  t.b11 = (y1 * WW + x1) * CC;
  t.fy = cy - fy0;
  t.fx = cx - fx0;
  return t;
}

// ---- Prep: X fp32->bf16, and W [k][f] -> Wt [f][k] bf16 (unchanged, verified)
__global__ void prep_kernel(const float* __restrict__ X, const float* __restrict__ W,
                            unsigned short* __restrict__ Xb, unsigned short* __restrict__ Wt) {
  const int blk = blockIdx.x;
  if (blk < XCVT_BLOCKS) {                  // X convert, 8 elems/thread
    const int t = blk * 256 + threadIdx.x;
    const float4* src = (const float4*)(X + (size_t)t * 8);
    float4 a = src[0], b2 = src[1];
    bf16x8 o;
    o[0] = (short)f2bf(a.x);  o[1] = (short)f2bf(a.y);
    o[2] = (short)f2bf(a.z);  o[3] = (short)f2bf(a.w);
    o[4] = (short)f2bf(b2.x); o[5] = (short)f2bf(b2.y);
    o[6] = (short)f2bf(b2.z); o[7] = (short)f2bf(b2.w);
    *(bf16x8*)(Xb + (size_t)t * 8) = o;
  } else {                                  // W transpose: thread = (f, 8 k's)
    const int t = (blk - XCVT_BLOCKS) * 256 + threadIdx.x;  // 0..36863
    const int f = t & 255;
    const int k0 = (t >> 8) * 8;
    unsigned short o[8];
#pragma unroll
    for (int i2 = 0; i2 < 8; ++i2)
      o[i2] = f2bf(W[(size_t)(k0 + i2) * FF + f]);
    *(uint4*)(Wt + (size_t)f * KD + k0) = *(uint4*)o;
  }
}

// ---- Fused interp+GEMM: block = one image row = 64 M x 256 F, K = 1152.
// Per kt (64 k = half a tap): frag reads -> barrier -> {gathers + B-DMA issue}
// -> 32 MFMA -> lerp+ds_write smA -> barrier. Single-buffered smA(8K)+smB(32K).
__global__ __launch_bounds__(256, 2) void fused_kernel(
    const unsigned short* __restrict__ Xb, const float* __restrict__ Off,
    const unsigned short* __restrict__ Wt, const float* __restrict__ bias,
    float* __restrict__ Out)
{
  __shared__ unsigned short smA[64 * 64];     // 8 KB : 64 M-rows x 64 k (XOR-swizzled chunks)
  __shared__ unsigned short smB[256 * 64];    // 32 KB: 256 F-rows x 64 k (XOR-swizzled chunks)

  const int blk = blockIdx.x;       // 0..511
  const int b   = blk & 7;          // batch -> XCD locality (Xb slice L2-resident)
  const int i   = blk >> 3;         // image row y; the 64 positions are x = 0..63
  const int m0  = (b * 64 + i) * 64;
  const int tid = threadIdx.x;
  const int wave = tid >> 6, lane = tid & 63;
  const int wf   = wave * 64;       // wave: 64M x 64F -> zero B-frag duplication
  const int arow = lane & 15, aq = lane >> 4;
  const int srow = tid >> 3, sch = tid & 7;   // B staging: 8 rows/thread
  const int p = tid >> 2, c0 = tid & 3;       // interp: pos p, chunks c0 & c0+4

  const unsigned short* xb = Xb + (size_t)b * (HH * WW * CC);
  const float* offp = Off + ((size_t)(b * HH + i) * WW + p) * (2 * NTAP);

  floatx4 acc[4][4];
#pragma unroll
  for (int mt = 0; mt < 4; ++mt)
#pragma unroll
    for (int ft = 0; ft < 4; ++ft)
      acc[mt][ft] = (floatx4){0.f, 0.f, 0.f, 0.f};

  // LDS dest = wave-uniform base + lane*16 (linear); swizzle applied on global side.
#define STAGE_B(KT)                                                                  \
  {                                                                                  \
    _Pragma("unroll")                                                                \
    for (int q2 = 0; q2 < 8; ++q2) {                                                 \
      const int row = q2 * 32 + srow;                                                \
      const int chp = sch ^ (row & 7);                                               \
      const unsigned short* gp = Wt + (size_t)row * KD + (KT) * 64 + chp * 8;        \
      unsigned short* l = (unsigned short*)&smB[row * 64 + sch * 8];                 \
      __builtin_amdgcn_global_load_lds(                                              \
          (const __attribute__((address_space(1))) unsigned int*)gp,                 \
          (__attribute__((address_space(3))) unsigned int*)l, 16, 0, 0);             \
    }                                                                                \
  }

  // ---- prologue: interp tile kt=0 + stage B tile 0
  {
    ITap t = interp_setup(offp, i, p, 0);
#pragma unroll
    for (int cc = 0; cc < 2; ++cc) {
      const int c = c0 + cc * 4;
      const int ch = c << 3;   // tap 0, low half -> global chunk = c
      uint4 q00 = *(const uint4*)(xb + t.b00 + ch);
      uint4 q10 = *(const uint4*)(xb + t.b10 + ch);
      uint4 q01 = *(const uint4*)(xb + t.b01 + ch);
      uint4 q11 = *(const uint4*)(xb + t.b11 + ch);
      unsigned ow0 = lerp_word(q00.x, q10.x, q01.x, q11.x, t.fy, t.fx);
      unsigned ow1 = lerp_word(q00.y, q10.y, q01.y, q11.y, t.fy, t.fx);
      unsigned ow2 = lerp_word(q00.z, q10.z, q01.z, q11.z, t.fy, t.fx);
      unsigned ow3 = lerp_word(q00.w, q10.w, q01.w, q11.w, t.fy, t.fx);
      *(uint4*)&smA[p * 64 + ((c ^ (p & 7)) << 3)] = make_uint4(ow0, ow1, ow2, ow3);
    }
    STAGE_B(0)
  }
  __syncthreads();

  for (int kt = 0; kt < 18; ++kt) {
    // ---- phase 1: pull this tile's fragments into registers
    bf16x8 afr[2][4], bfr[2][4];
#pragma unroll
    for (int ks = 0; ks < 2; ++ks) {
      const int slot = (((ks * 4 + aq) ^ (arow & 7)) << 3);
#pragma unroll
      for (int mt = 0; mt < 4; ++mt)
        afr[ks][mt] = *(const bf16x8*)&smA[(mt * 16 + arow) * 64 + slot];
#pragma unroll
      for (int ft = 0; ft < 4; ++ft)
        bfr[ks][ft] = *(const bf16x8*)&smB[(wf + ft * 16 + arow) * 64 + slot];
    }
    __syncthreads();   // buffers free for overwrite

    // ---- phase 2a: issue next tile's gathers + B DMA (hide under MFMA)
    const int nx = kt + 1;
    ITap t;
    uint4 g[2][4];
    if (nx < 18) {
      t = interp_setup(offp, i, p, nx);
      const int gc = (nx & 1) << 3;
#pragma unroll
      for (int cc = 0; cc < 2; ++cc) {
        const int ch = (gc + c0 + cc * 4) << 3;
        g[cc][0] = *(const uint4*)(xb + t.b00 + ch);
        g[cc][1] = *(const uint4*)(xb + t.b10 + ch);
        g[cc][2] = *(const uint4*)(xb + t.b01 + ch);
        g[cc][3] = *(const uint4*)(xb + t.b11 + ch);
      }
      STAGE_B(nx)
    }

    // ---- phase 2b: MFMA on registers
#pragma unroll
    for (int ks = 0; ks < 2; ++ks)
#pragma unroll
      for (int mt = 0; mt < 4; ++mt)
#pragma unroll
        for (int ft = 0; ft < 4; ++ft)
          acc[mt][ft] = __builtin_amdgcn_mfma_f32_16x16x32_bf16(
              afr[ks][mt], bfr[ks][ft], acc[mt][ft], 0, 0, 0);

    // ---- phase 2c: finish interp of next tile, write to smA
    if (nx < 18) {
#pragma unroll
      for (int cc = 0; cc < 2; ++cc) {
        const int c = c0 + cc * 4;
        uint4 q00 = g[cc][0], q10 = g[cc][1], q01 = g[cc][2], q11 = g[cc][3];
        unsigned ow0 = lerp_word(q00.x, q10.x, q01.x, q11.x, t.fy, t.fx);
        unsigned ow1 = lerp_word(q00.y, q10.y, q01.y, q11.y, t.fy, t.fx);
        unsigned ow2 = lerp_word(q00.z, q10.z, q01.z, q11.z, t.fy, t.fx);
        unsigned ow3 = lerp_word(q00.w, q10.w, q01.w, q11.w, t.fy, t.fx);
        *(uint4*)&smA[p * 64 + ((c ^ (p & 7)) << 3)] = make_uint4(ow0, ow1, ow2, ow3);
      }
    }
    __syncthreads();   // drains B-DMA (vmcnt) + smA writes (lgkm)
  }
#undef STAGE_B

  // ---- epilogue
  float bv[4];
#pragma unroll
  for (int ft = 0; ft < 4; ++ft)
    bv[ft] = bias[wf + ft * 16 + arow];
#pragma unroll
  for (int mt = 0; mt < 4; ++mt) {
#pragma unroll
    for (int ft = 0; ft < 4; ++ft) {
      const int f = wf + ft * 16 + arow;
#pragma unroll
      for (int r = 0; r < 4; ++r) {
        const int m = m0 + mt * 16 + aq * 4 + r;
        Out[(size_t)m * FF + f] = acc[mt][ft][r] + bv[ft];
      }
    }
  }
}

extern "C" void kernel_launch(void* const* d_in, const int* in_sizes, int n_in,
                              void* d_out, int out_size, void* d_ws, size_t ws_size,
                              hipStream_t stream) {
  const float* X    = (const float*)d_in[0];
  const float* Off  = (const float*)d_in[1];
  const float* W    = (const float*)d_in[2];
  const float* bias = (const float*)d_in[3];
  float* Out = (float*)d_out;

  unsigned short* Wt = (unsigned short*)d_ws;                  // 294912 shorts
  unsigned short* Xb = Wt + (size_t)FF * KD;                   // 4194304 shorts

  prep_kernel<<<XCVT_BLOCKS + WT_BLOCKS, 256, 0, stream>>>(X, W, Xb, Wt);
  fused_kernel<<<512, 256, 0, stream>>>(Xb, Off, Wt, bias, Out);
}

// Round 2
// 112.563 us; speedup vs baseline: 1.1518x; 1.0666x over previous
//
#include <hip/hip_runtime.h>

#define HH 64
#define WW 64
#define CC 128
#define FF 256
#define NTAP 9
#define KD 1152   // NTAP*CC
#define XELEMS (8 * HH * WW * CC)         // 4194304
#define XCVT_BLOCKS (XELEMS / (256 * 8))  // 2048
#define WT_BLOCKS 144                     // 36864 threads, 8 k each

typedef __attribute__((ext_vector_type(8))) short bf16x8;
typedef __attribute__((ext_vector_type(4))) float floatx4;

__device__ inline unsigned short f2bf(float v) {
  union { float f; unsigned u; } c; c.f = v;
  unsigned r = (c.u + 0x7FFFu + ((c.u >> 16) & 1u)) >> 16;  // RNE
  return (unsigned short)r;
}
__device__ inline float bflo(unsigned u) {
  union { unsigned u; float f; } c; c.u = u << 16; return c.f;
}
__device__ inline float bfhi(unsigned u) {
  union { unsigned u; float f; } c; c.u = u & 0xFFFF0000u; return c.f;
}
// HW RNE pack: bf16(lo) | bf16(hi)<<16 — identical rounding to f2bf for finite inputs.
__device__ inline unsigned cvt_pk_bf16(float lo, float hi) {
  unsigned r;
  asm("v_cvt_pk_bf16_f32 %0, %1, %2" : "=v"(r) : "v"(lo), "v"(hi));
  return r;
}

// Bilinear lerp of one 32-bit word (2 bf16 channels). Same arithmetic order as verified.
__device__ inline unsigned lerp_word(unsigned u00, unsigned u10, unsigned u01, unsigned u11,
                                     float fy, float fx) {
  float v00 = bflo(u00), v10 = bflo(u10), v01 = bflo(u01), v11 = bflo(u11);
  float tx = v00 + (v10 - v00) * fy;
  float tb = v01 + (v11 - v01) * fy;
  float rlo = tx + (tb - tx) * fx;
  v00 = bfhi(u00); v10 = bfhi(u10); v01 = bfhi(u01); v11 = bfhi(u11);
  tx = v00 + (v10 - v00) * fy;
  tb = v01 + (v11 - v01) * fy;
  float rhi = tx + (tb - tx) * fx;
  return cvt_pk_bf16(rlo, rhi);
}

// Tap offsets packed 2 bits each (meshgrid-faithful order):
// c_iy = {0,0,1,2,2,1,0,2,1} -> 0x18690 ; c_ix = {0,1,1,2,0,2,1,0,2} -> 0x21894
#define IY_PACK 0x18690
#define IX_PACK 0x21894

struct ITap { int b00, b10, b01, b11; float fy, fx; };

__device__ inline ITap interp_setup(const float* __restrict__ offp, int i, int p, int nx) {
  const int n = nx >> 1;
  const float2 o2 = *(const float2*)(offp + 2 * n);
  float cy = (float)(i - 1 + ((IY_PACK >> (2 * n)) & 3)) + o2.x;
  float cx = (float)(p - 1 + ((IX_PACK >> (2 * n)) & 3)) + o2.y;
  cy = fminf(fmaxf(cy, 0.f), 63.f);
  cx = fminf(fmaxf(cx, 0.f), 63.f);
  const float fy0 = floorf(cy), fx0 = floorf(cx);
  const int y0 = (int)fy0, y1 = (int)ceilf(cy);
  const int x0 = (int)fx0, x1 = (int)ceilf(cx);
  ITap t;
  t.b00 = (y0 * WW + x0) * CC;
  t.b10 = (y1 * WW + x0) * CC;
  t.b01 = (y0 * WW + x1) * CC;
  t.b11 = (y1 * WW + x1) * CC;
  t.fy = cy - fy0;
  t.fx = cx - fx0;
  return t;
}

// ---- Prep: X fp32->bf16, and W [k][f] -> Wt [f][k] bf16 (unchanged, verified)
__global__ void prep_kernel(const float* __restrict__ X, const float* __restrict__ W,
                            unsigned short* __restrict__ Xb, unsigned short* __restrict__ Wt) {
  const int blk = blockIdx.x;
  if (blk < XCVT_BLOCKS) {                  // X convert, 8 elems/thread
    const int t = blk * 256 + threadIdx.x;
    const float4* src = (const float4*)(X + (size_t)t * 8);
    float4 a = src[0], b2 = src[1];
    bf16x8 o;
    o[0] = (short)f2bf(a.x);  o[1] = (short)f2bf(a.y);
    o[2] = (short)f2bf(a.z);  o[3] = (short)f2bf(a.w);
    o[4] = (short)f2bf(b2.x); o[5] = (short)f2bf(b2.y);
    o[6] = (short)f2bf(b2.z); o[7] = (short)f2bf(b2.w);
    *(bf16x8*)(Xb + (size_t)t * 8) = o;
  } else {                                  // W transpose: thread = (f, 8 k's)
    const int t = (blk - XCVT_BLOCKS) * 256 + threadIdx.x;  // 0..36863
    const int f = t & 255;
    const int k0 = (t >> 8) * 8;
    unsigned short o[8];
#pragma unroll
    for (int i2 = 0; i2 < 8; ++i2)
      o[i2] = f2bf(W[(size_t)(k0 + i2) * FF + f]);
    *(uint4*)(Wt + (size_t)f * KD + k0) = *(uint4*)o;
  }
}

// ---- Fused interp+GEMM: block = one image row = 64 M x 256 F, K = 1152.
// 512 threads = 8 waves (2M x 4F grid of 32Mx64F waves) -> 16 waves/CU for latency hiding.
// Per kt (64 k = half a tap): frag reads -> barrier -> {gathers + B-DMA issue}
// -> 16 MFMA/wave -> lerp+ds_write smA -> barrier. Single-buffered smA(8K)+smB(32K).
__global__ __launch_bounds__(512, 4) void fused_kernel(
    const unsigned short* __restrict__ Xb, const float* __restrict__ Off,
    const unsigned short* __restrict__ Wt, const float* __restrict__ bias,
    float* __restrict__ Out)
{
  __shared__ unsigned short smA[64 * 64];     // 8 KB : 64 M-rows x 64 k (XOR-swizzled chunks)
  __shared__ unsigned short smB[256 * 64];    // 32 KB: 256 F-rows x 64 k (XOR-swizzled chunks)

  const int blk = blockIdx.x;       // 0..511
  const int b   = blk & 7;          // batch -> XCD locality (Xb slice L2-resident)
  const int i   = blk >> 3;         // image row y; positions are x = 0..63
  const int m0  = (b * 64 + i) * 64;
  const int tid = threadIdx.x;
  const int wave = tid >> 6, lane = tid & 63;
  const int wm   = (wave & 1) * 32;     // wave: 32 M x 64 F
  const int wf   = (wave >> 1) * 64;
  const int arow = lane & 15, aq = lane >> 4;
  const int p  = tid >> 3;          // interp: position 0..63
  const int c0 = tid & 7;           // interp: one 8-channel chunk (8 lanes -> 128B/corner)

  const unsigned short* xb = Xb + (size_t)b * (HH * WW * CC);
  const float* offp = Off + ((size_t)(b * 64 + i) * 64 + p) * (2 * NTAP);

  floatx4 acc[2][4];
#pragma unroll
  for (int mt = 0; mt < 2; ++mt)
#pragma unroll
    for (int ft = 0; ft < 4; ++ft)
      acc[mt][ft] = (floatx4){0.f, 0.f, 0.f, 0.f};

  // LDS dest = wave-uniform base + lane*16 (linear in tid); swizzle on global side.
#define STAGE_B(KT)                                                                  \
  {                                                                                  \
    _Pragma("unroll")                                                                \
    for (int q2 = 0; q2 < 4; ++q2) {                                                 \
      const int row = q2 * 64 + (tid >> 3);                                          \
      const int chp = c0 ^ (row & 7);                                                \
      const unsigned short* gp = Wt + (size_t)row * KD + (KT) * 64 + chp * 8;        \
      unsigned short* l = (unsigned short*)&smB[row * 64 + c0 * 8];                  \
      __builtin_amdgcn_global_load_lds(                                              \
          (const __attribute__((address_space(1))) unsigned int*)gp,                 \
          (__attribute__((address_space(3))) unsigned int*)l, 16, 0, 0);             \
    }                                                                                \
  }

  // ---- prologue: interp tile kt=0 + stage B tile 0
  {
    ITap t = interp_setup(offp, i, p, 0);
    const int ch = c0 * 8;   // tap 0, low half
    uint4 q00 = *(const uint4*)(xb + t.b00 + ch);
    uint4 q10 = *(const uint4*)(xb + t.b10 + ch);
    uint4 q01 = *(const uint4*)(xb + t.b01 + ch);
    uint4 q11 = *(const uint4*)(xb + t.b11 + ch);
    unsigned ow0 = lerp_word(q00.x, q10.x, q01.x, q11.x, t.fy, t.fx);
    unsigned ow1 = lerp_word(q00.y, q10.y, q01.y, q11.y, t.fy, t.fx);
    unsigned ow2 = lerp_word(q00.z, q10.z, q01.z, q11.z, t.fy, t.fx);
    unsigned ow3 = lerp_word(q00.w, q10.w, q01.w, q11.w, t.fy, t.fx);
    *(uint4*)&smA[p * 64 + ((c0 ^ (p & 7)) << 3)] = make_uint4(ow0, ow1, ow2, ow3);
    STAGE_B(0)
  }
  __syncthreads();

  for (int kt = 0; kt < 18; ++kt) {
    // ---- phase 1: pull this tile's fragments into registers
    bf16x8 afr[2][2], bfr[2][4];
#pragma unroll
    for (int ks = 0; ks < 2; ++ks) {
      const int slot = (((ks * 4 + aq) ^ (arow & 7)) << 3);
#pragma unroll
      for (int mt = 0; mt < 2; ++mt)
        afr[ks][mt] = *(const bf16x8*)&smA[(wm + mt * 16 + arow) * 64 + slot];
#pragma unroll
      for (int ft = 0; ft < 4; ++ft)
        bfr[ks][ft] = *(const bf16x8*)&smB[(wf + ft * 16 + arow) * 64 + slot];
    }
    __syncthreads();   // buffers free for overwrite

    // ---- phase 2a: issue next tile's gathers + B DMA (hide under MFMA)
    const int nx = kt + 1;
    ITap t;
    uint4 g00, g10, g01, g11;
    if (nx < 18) {
      t = interp_setup(offp, i, p, nx);
      const int ch = ((nx & 1) * 8 + c0) * 8;
      g00 = *(const uint4*)(xb + t.b00 + ch);
      g10 = *(const uint4*)(xb + t.b10 + ch);
      g01 = *(const uint4*)(xb + t.b01 + ch);
      g11 = *(const uint4*)(xb + t.b11 + ch);
      STAGE_B(nx)
    }

    // ---- phase 2b: MFMA on registers
#pragma unroll
    for (int ks = 0; ks < 2; ++ks)
#pragma unroll
      for (int mt = 0; mt < 2; ++mt)
#pragma unroll
        for (int ft = 0; ft < 4; ++ft)
          acc[mt][ft] = __builtin_amdgcn_mfma_f32_16x16x32_bf16(
              afr[ks][mt], bfr[ks][ft], acc[mt][ft], 0, 0, 0);

    // ---- phase 2c: finish interp of next tile, write to smA
    if (nx < 18) {
      unsigned ow0 = lerp_word(g00.x, g10.x, g01.x, g11.x, t.fy, t.fx);
      unsigned ow1 = lerp_word(g00.y, g10.y, g01.y, g11.y, t.fy, t.fx);
      unsigned ow2 = lerp_word(g00.z, g10.z, g01.z, g11.z, t.fy, t.fx);
      unsigned ow3 = lerp_word(g00.w, g10.w, g01.w, g11.w, t.fy, t.fx);
      *(uint4*)&smA[p * 64 + ((c0 ^ (p & 7)) << 3)] = make_uint4(ow0, ow1, ow2, ow3);
    }
    __syncthreads();   // drains B-DMA (vmcnt) + smA writes (lgkm)
  }
#undef STAGE_B

  // ---- epilogue
  float bv[4];
#pragma unroll
  for (int ft = 0; ft < 4; ++ft)
    bv[ft] = bias[wf + ft * 16 + arow];
#pragma unroll
  for (int mt = 0; mt < 2; ++mt) {
#pragma unroll
    for (int ft = 0; ft < 4; ++ft) {
      const int f = wf + ft * 16 + arow;
#pragma unroll
      for (int r = 0; r < 4; ++r) {
        const int m = m0 + wm + mt * 16 + aq * 4 + r;
        Out[(size_t)m * FF + f] = acc[mt][ft][r] + bv[ft];
      }
    }
  }
}

extern "C" void kernel_launch(void* const* d_in, const int* in_sizes, int n_in,
                              void* d_out, int out_size, void* d_ws, size_t ws_size,
                              hipStream_t stream) {
  const float* X    = (const float*)d_in[0];
  const float* Off  = (const float*)d_in[1];
  const float* W    = (const float*)d_in[2];
  const float* bias = (const float*)d_in[3];
  float* Out = (float*)d_out;

  unsigned short* Wt = (unsigned short*)d_ws;                  // 294912 shorts
  unsigned short* Xb = Wt + (size_t)FF * KD;                   // 4194304 shorts

  prep_kernel<<<XCVT_BLOCKS + WT_BLOCKS, 256, 0, stream>>>(X, W, Xb, Wt);
  fused_kernel<<<512, 512, 0, stream>>>(Xb, Off, Wt, bias, Out);
}